// Round 5
// baseline (1656.673 us; speedup 1.0000x reference)
//
#include <hip/hip_runtime.h>
#include <hip/hip_bf16.h>

// HetGTAN 5-hop hetero graph attention, MI355X.
// Round 8: resubmit of Round 7 (container-level infra failure, no verdict).
// (1) fc1 as LDS-staged GEMM: async global_load_lds width-16, double-buffered
// K-step-128 tiles, source-side XOR swizzle + matching read-side XOR.
// (2) hop_h1 fused into hop_agg (h1 computed in-register from the h[t] row
// the aggregation loads anyway; kills the per-edge h1 gather + 5 launches).

#define NP 100000
#define NA 200000
#define NSJ 1000
#define EPA 800000
#define EAP 800000
#define EPS 100000
#define ESP 100000
#define ETOT 1800000
// source-slot concat: [paper(pa) | author(ap) | paper(ps) | subject(sp)]
#define NS_TOT 401000
#define NSRC 301000
#define NCHUNK 392  // ceil(401000/1024)
#define NSGRP 25063 // ceil(401000/16)
#define SCAT_SLICE 4096
#define NSLICE ((ETOT + SCAT_SLICE - 1) / SCAT_SLICE)   // 440
#define BKT ((ETOT + 7) / 8)                            // 225000

typedef __attribute__((ext_vector_type(8))) short bf16x8;
typedef __attribute__((ext_vector_type(4))) float floatx4;
typedef __attribute__((ext_vector_type(8))) float floatx8;
typedef __hip_bfloat16 bf16;

__device__ __forceinline__ float bf2f(bf16 v) { return __bfloat162float(v); }
__device__ __forceinline__ float us2f(unsigned short u) { return __uint_as_float((unsigned)u << 16); }
__device__ __forceinline__ float eluf(float x) { return x > 0.f ? x : __expf(x) - 1.f; }
__device__ __forceinline__ unsigned short f2bf_bits(float f) {
    unsigned int u = __float_as_uint(f);
    return (unsigned short)((u + 0x7FFFu + ((u >> 16) & 1u)) >> 16);  // RNE
}

// async global->LDS, 16 B per lane, linear LDS dest (base + lane*16)
__device__ __forceinline__ void gload_lds16(const void* g, void* l) {
    __builtin_amdgcn_global_load_lds(
        (const __attribute__((address_space(1))) unsigned int*)g,
        (__attribute__((address_space(3))) unsigned int*)l, 16, 0, 0);
}

// fp32->bf16 MFMA fragment conversion load (fallback path)
__device__ __forceinline__ bf16x8 load_frag_f32(const void* base, size_t off) {
    const float4* f = (const float4*)((const float*)base + off);  // off%8==0 -> 16B aligned
    float4 a = f[0], b = f[1];
    bf16x8 r;
    r[0] = (short)f2bf_bits(a.x); r[1] = (short)f2bf_bits(a.y);
    r[2] = (short)f2bf_bits(a.z); r[3] = (short)f2bf_bits(a.w);
    r[4] = (short)f2bf_bits(b.x); r[5] = (short)f2bf_bits(b.y);
    r[6] = (short)f2bf_bits(b.z); r[7] = (short)f2bf_bits(b.w);
    return r;
}

// edge -> global source slot / target id from the 4 input edge arrays
__device__ __forceinline__ int edge_src(int e, const int* pa, const int* ap,
                                        const int* ps, const int* sp) {
    if (e < EPA)                  return pa[e];
    if (e < EPA + EAP)            return NP + ap[e - EPA];
    if (e < EPA + EAP + EPS)      return NP + NA + ps[e - (EPA + EAP)];
    return NP + NA + NP + sp[e - (EPA + EAP + EPS)];
}
__device__ __forceinline__ int edge_tgt(int e, const int* pa, const int* ap,
                                        const int* ps, const int* sp) {
    if (e < EPA)                  return pa[EPA + e];
    if (e < EPA + EAP)            return ap[EAP + (e - EPA)];
    if (e < EPA + EAP + EPS)      return ps[EPS + (e - (EPA + EAP))];
    return sp[ESP + (e - (EPA + EAP + EPS))];
}

// ---------------- dtype detection ----------------
__global__ void detect_dtype(const unsigned int* __restrict__ xraw, int* __restrict__ flag) {
    int t = threadIdx.x;   // 64 threads
    int hits = 0;
#pragma unroll
    for (int i = 0; i < 16; ++i) {
        unsigned int w = xraw[t * 16 + i];
        unsigned int lo = w & 0xFFFFu;
        unsigned int e = (lo >> 7) & 0xFFu;   // bf16 exponent field of low half
        if (lo == 0u || (e >= 110u && e <= 140u)) hits++;
    }
#pragma unroll
    for (int o = 32; o; o >>= 1) hits += __shfl_xor(hits, o);
    if (t == 0) *flag = (hits > 512) ? 1 : 0;   // bf16 ~99% hit, fp32 ~12%
}

// ---------------- merged param normalization to fp32 ----------------
__global__ void conv_all(const void* a1, const void* a2, const void* lw, const void* w2,
                         const void* b2, const void* bp, const void* ba, const void* bs,
                         float* a1c, float* a2c, float* lwc, float* w2c, float* b2c,
                         float* b1p, float* b1a, float* b1s, const int* __restrict__ flagp)
{
    int i = blockIdx.x * blockDim.x + threadIdx.x;
    int isb = *flagp;
    auto cv = [&](const void* s, int j) -> float {
        return isb ? bf2f(((const bf16*)s)[j]) : ((const float*)s)[j];
    };
    if (i < 1280)      a1c[i] = cv(a1, i);
    else if (i < 2560) a2c[i - 1280] = cv(a2, i - 1280);
    else if (i < 2580) lwc[i - 2560] = cv(lw, i - 2560);
    else if (i < 3604) w2c[i - 2580] = cv(w2, i - 2580);
    else if (i < 3620) b2c[i - 3604] = cv(b2, i - 3604);
    else if (i < 3684) b1p[i - 3620] = cv(bp, i - 3620);
    else if (i < 3748) b1a[i - 3684] = cv(ba, i - 3684);
    else if (i < 3812) b1s[i - 3748] = cv(bs, i - 3748);
}

// -------- pack attn vectors as B matrices for MFMA: per k, [16 rows][64] ------
__global__ void pack_attn(const float* __restrict__ a1c, const float* __restrict__ a2c,
                          bf16* __restrict__ apack)
{
    int i = blockIdx.x * blockDim.x + threadIdx.x;   // 4 k-slots * 1024
    if (i >= 4096) return;
    int k = i >> 10, rf = i & 1023;
    int row = rf >> 6;
    int f = rf & 63;
    float v = 0.f;
    if (row < 5)       v = a1c[(row * 4 + k) * 64 + f];
    else if (row < 10) v = a2c[((row - 5) * 4 + k) * 64 + f];
    unsigned short hi = f2bf_bits(v);
    float lo = v - us2f(hi);
    unsigned short* up = (unsigned short*)apack;
    up[(size_t)(k * 2) * 1024 + rf]     = hi;
    up[(size_t)(k * 2 + 1) * 1024 + rf] = f2bf_bits(lo);
}

// ---------------- fc1: x = relu(X @ W^T + b), W is [64,K]; writes bf16 -------
// LDS-staged pipeline: 64 rows/block, K-step 128, double-buffered 16 KB tiles
// staged via async global_load_lds (contiguous 1 KB per instruction). LDS
// chunks XOR-swizzled via pre-swizzled GLOBAL source (linear LDS dest) so the
// ds_read_b128 fragment reads don't bank-conflict.
template<int K>
__global__ void fc1_lds(const void* __restrict__ X, const void* __restrict__ W,
                        const float* __restrict__ Bb, int N,
                        bf16* __restrict__ xo, const int* __restrict__ flagp)
{
    constexpr int NSTEP = K / 128;
    __shared__ __align__(16) unsigned char lds[2][64 * 256];   // [buf][row][chunk*16B]
    int isb = *flagp;
    int lane = threadIdx.x & 63;
    int wv = threadIdx.x >> 6;
    int row0 = blockIdx.x * 64;
    int m = lane & 15, kq = lane >> 4;
    floatx4 acc[4] = {};

    if (isb) {
        const bf16* Xb = (const bf16*)X;
        const bf16* Wb = (const bf16*)W;
        auto stage = [&](int s, int b) {
#pragma unroll
            for (int it = 0; it < 4; ++it) {
                int slotbase = (it * 4 + wv) * 64;    // wave-uniform
                int slot = slotbase + lane;
                int r = slot >> 4;
                int c = slot & 15;
                int rc = row0 + r; if (rc >= N) rc = N - 1;   // tail clamp
                int cs = c ^ (r & 15);                 // pre-swizzled source chunk
                const bf16* src = Xb + (size_t)rc * K + s * 128 + cs * 8;
                gload_lds16(src, &lds[b][slotbase * 16]);
            }
        };
        stage(0, 0);
        asm volatile("s_waitcnt vmcnt(0)" ::: "memory");
        __syncthreads();
        int R = wv * 16 + m;
#pragma unroll
        for (int s = 0; s < NSTEP; ++s) {
            if (s + 1 < NSTEP) stage(s + 1, (s + 1) & 1);   // async prefetch
            const unsigned char* bufp = lds[s & 1];
#pragma unroll
            for (int i = 0; i < 4; ++i) {
                int cs = (i * 4 + kq) ^ (R & 15);
                bf16x8 av = *(const bf16x8*)(bufp + R * 256 + cs * 16);
                int kg = s * 128 + i * 32 + kq * 8;
#pragma unroll
                for (int nb = 0; nb < 4; ++nb) {
                    bf16x8 bv = *(const bf16x8*)(Wb + (size_t)(nb * 16 + m) * K + kg);
                    acc[nb] = __builtin_amdgcn_mfma_f32_16x16x32_bf16(av, bv, acc[nb], 0, 0, 0);
                }
            }
            asm volatile("s_waitcnt vmcnt(0)" ::: "memory");   // prefetch landed
            __syncthreads();                                   // tile consumed by all waves
        }
    } else {
        // fp32 fallback: direct converting loads (rare path)
        int arow = row0 + wv * 16 + m;
        if (arow >= N) arow = N - 1;
#pragma unroll 4
        for (int i = 0; i < K / 32; ++i) {
            int k0 = i * 32 + kq * 8;
            bf16x8 av = load_frag_f32(X, (size_t)arow * K + k0);
#pragma unroll
            for (int nb = 0; nb < 4; ++nb) {
                bf16x8 bv = load_frag_f32(W, (size_t)(nb * 16 + m) * K + k0);
                acc[nb] = __builtin_amdgcn_mfma_f32_16x16x32_bf16(av, bv, acc[nb], 0, 0, 0);
            }
        }
    }
#pragma unroll
    for (int nb = 0; nb < 4; ++nb) {
#pragma unroll
        for (int r = 0; r < 4; ++r) {
            int row = row0 + wv * 16 + kq * 4 + r;   // C/D: row=(lane>>4)*4+reg, col=lane&15
            if (row < N) {
                int f = nb * 16 + m;
                float v = acc[nb][r] + Bb[f];
                xo[(size_t)row * 64 + f] = __float2bfloat16(fmaxf(v, 0.f));
            }
        }
    }
}

// ------- precompute x1 = x.a1, w2 = exp(lrelu(x1 + x.a2)) for all 5 hops -------
__global__ void precompute_xw_mfma(const bf16* __restrict__ xP, const bf16* __restrict__ xA,
                                   const bf16* __restrict__ xS,
                                   const bf16* __restrict__ apack,
                                   float* __restrict__ x1buf, float* __restrict__ w2buf)
{
    int wv = threadIdx.x >> 6;
    int lane = threadIdx.x & 63;
    int grp = blockIdx.x * 4 + wv;
    if (grp >= NSGRP) return;
    int base = grp * 16;
    int k, n0, nmax; const bf16* x;
    if (base < NP)                { k = 0; n0 = base;                  nmax = NP;  x = xP; }
    else if (base < NP + NA)      { k = 1; n0 = base - NP;             nmax = NA;  x = xA; }
    else if (base < NP + NA + NP) { k = 2; n0 = base - (NP + NA);      nmax = NP;  x = xP; }
    else                          { k = 3; n0 = base - (NP + NA + NP); nmax = NSJ; x = xS; }
    int m = lane & 15, kq = lane >> 4;
    int arow = n0 + m;
    if (arow >= nmax) arow = nmax - 1;      // clamp (subject tail)
    const bf16* bh = apack + (size_t)(k * 2) * 1024;
    const bf16* bl = bh + 1024;
    floatx4 acc = {};
#pragma unroll
    for (int ks = 0; ks < 64; ks += 32) {
        int k0 = ks + kq * 8;
        bf16x8 av  = *(const bf16x8*)(x  + (size_t)arow * 64 + k0);
        bf16x8 bvh = *(const bf16x8*)(bh + m * 64 + k0);
        bf16x8 bvl = *(const bf16x8*)(bl + m * 64 + k0);
        acc = __builtin_amdgcn_mfma_f32_16x16x32_bf16(av, bvh, acc, 0, 0, 0);
        acc = __builtin_amdgcn_mfma_f32_16x16x32_bf16(av, bvl, acc, 0, 0, 0);
    }
#pragma unroll
    for (int r = 0; r < 4; ++r) {
        float v = acc[r];
        float d2 = __shfl(v, lane + 5);     // same kq for m<11; only m<5 consumed
        int node = base + kq * 4 + r;
        if (m < 5 && node < NS_TOT) {
            x1buf[m * NS_TOT + node] = v;
            float z = v + d2;
            w2buf[m * NS_TOT + node] = __expf(z > 0.f ? z : 0.2f * z);
        }
    }
}

// ---------------- CSR build: rank -> scan -> pos -> bucketed scatter ----------------
__global__ void csr_rank(const int* __restrict__ pa, const int* __restrict__ ap,
                         const int* __restrict__ ps, const int* __restrict__ sp,
                         int* __restrict__ cnt, int* __restrict__ rank)
{
    int e = blockIdx.x * blockDim.x + threadIdx.x;
    if (e >= ETOT) return;
    int g = edge_src(e, pa, ap, ps, sp);
    rank[e] = atomicAdd(&cnt[g], 1);
}

__global__ void scan_reduce(const int* __restrict__ cnt, int* __restrict__ partial)
{
    __shared__ int s[256];
    int base = blockIdx.x * 1024 + threadIdx.x * 4;
    int sum = 0;
#pragma unroll
    for (int r = 0; r < 4; ++r) { int i = base + r; if (i < NS_TOT) sum += cnt[i]; }
    s[threadIdx.x] = sum; __syncthreads();
    for (int o = 128; o; o >>= 1) {
        if (threadIdx.x < o) s[threadIdx.x] += s[threadIdx.x + o];
        __syncthreads();
    }
    if (!threadIdx.x) partial[blockIdx.x] = s[0];
}

__global__ void scan_partials(const int* __restrict__ partial, int* __restrict__ chunkoff)
{
    __shared__ int s[512];
    int t = threadIdx.x;
    int v = (t < NCHUNK) ? partial[t] : 0;
    s[t] = v; __syncthreads();
    for (int o = 1; o < 512; o <<= 1) {
        int add = (t >= o) ? s[t - o] : 0;
        __syncthreads();
        s[t] += add; __syncthreads();
    }
    if (t < NCHUNK) chunkoff[t] = s[t] - v;   // exclusive
}

__global__ void scan_write(const int* __restrict__ cnt, const int* __restrict__ chunkoff,
                           int* __restrict__ off)
{
    __shared__ int s[256];
    int t = threadIdx.x;
    int base = blockIdx.x * 1024 + t * 4;
    int v[4]; int tsum = 0;
#pragma unroll
    for (int r = 0; r < 4; ++r) { int i = base + r; v[r] = (i < NS_TOT) ? cnt[i] : 0; tsum += v[r]; }
    s[t] = tsum; __syncthreads();
    for (int o = 1; o < 256; o <<= 1) {
        int add = (t >= o) ? s[t - o] : 0;
        __syncthreads();
        s[t] += add; __syncthreads();
    }
    int excl = s[t] - tsum + chunkoff[blockIdx.x];
#pragma unroll
    for (int r = 0; r < 4; ++r) {
        int i = base + r;
        if (i < NS_TOT) { off[i] = excl; excl += v[r]; }
    }
}

__global__ void csr_pos(const int* __restrict__ pa, const int* __restrict__ ap,
                        const int* __restrict__ ps, const int* __restrict__ sp,
                        const int* __restrict__ rank, const int* __restrict__ off,
                        int* __restrict__ pos)
{
    int e = blockIdx.x * blockDim.x + threadIdx.x;
    if (e >= ETOT) return;
    int g = edge_src(e, pa, ap, ps, sp);
    pos[e] = off[g] + rank[e];
}

__global__ void csr_scatter(const int* __restrict__ pa, const int* __restrict__ ap,
                            const int* __restrict__ ps, const int* __restrict__ sp,
                            const int* __restrict__ pos, int* __restrict__ col)
{
    int b = blockIdx.x & 7;
    int slice = blockIdx.x >> 3;
    int lo = b * BKT;
    int hi = lo + BKT; if (hi > ETOT) hi = ETOT;
    int ebase = slice * SCAT_SLICE;
    int eend = ebase + SCAT_SLICE; if (eend > ETOT) eend = ETOT;
    for (int e = ebase + threadIdx.x; e < eend; e += 256) {
        int p = pos[e];
        if (p < lo || p >= hi) continue;
        col[p] = edge_tgt(e, pa, ap, ps, sp);
    }
}

// ------- per hop: 8 edges/wave x 8 feats/lane; h1[t] computed in-register -------
__device__ __forceinline__ floatx8 agg_et8(int g, int hop, int k, int eo, int fl, floatx8 xv,
    const float* __restrict__ x1buf, const float* __restrict__ w2buf,
    const float* __restrict__ a2c, const bf16* __restrict__ ht,
    const int* __restrict__ off, const int* __restrict__ deg, const int* __restrict__ col)
{
    float x1v = x1buf[hop * NS_TOT + g];
    const float4* a2p = (const float4*)(a2c + (hop * 4 + k) * 64 + fl * 8);
    float4 a2a = a2p[0], a2b = a2p[1];
    floatx8 acc = {};
    float dv = 0.f;
    int e0 = off[g];
    int e1 = e0 + deg[g];
    for (int e = e0 + eo; e < e1; e += 8) {
        int t = col[e];
        bf16x8 hv = *(const bf16x8*)(ht + (size_t)t * 64 + fl * 8);
        float hf[8];
#pragma unroll
        for (int j = 0; j < 8; ++j) hf[j] = us2f((unsigned short)hv[j]);
        // h1[t] = h[t].a2  (this lane's 8-feat slice, then 8-lane group tree)
        float h1t = hf[0] * a2a.x;
        h1t = fmaf(hf[1], a2a.y, h1t); h1t = fmaf(hf[2], a2a.z, h1t);
        h1t = fmaf(hf[3], a2a.w, h1t); h1t = fmaf(hf[4], a2b.x, h1t);
        h1t = fmaf(hf[5], a2b.y, h1t); h1t = fmaf(hf[6], a2b.z, h1t);
        h1t = fmaf(hf[7], a2b.w, h1t);
        h1t += __shfl_xor(h1t, 1);
        h1t += __shfl_xor(h1t, 2);
        h1t += __shfl_xor(h1t, 4);
        float z = x1v + h1t;
        float w1 = __expf(z > 0.f ? z : 0.2f * z);
#pragma unroll
        for (int j = 0; j < 8; ++j) acc[j] = fmaf(w1, hf[j], acc[j]);
        dv += w1;
    }
#pragma unroll
    for (int o = 8; o <= 32; o <<= 1) {   // combine the 8 edge groups
#pragma unroll
        for (int j = 0; j < 8; ++j) acc[j] += __shfl_xor(acc[j], o);
        dv += __shfl_xor(dv, o);
    }
    float w2v = w2buf[hop * NS_TOT + g];
    dv += w2v;
    float inv = 1.f / dv;
    floatx8 r;
#pragma unroll
    for (int j = 0; j < 8; ++j) r[j] = (acc[j] + w2v * xv[j]) * inv;
    return r;
}

__global__ void hop_agg(const bf16* __restrict__ hPo, const bf16* __restrict__ hAo,
                        const bf16* __restrict__ hSo,
                        const bf16* __restrict__ xP, const bf16* __restrict__ xA,
                        const bf16* __restrict__ xS,
                        const float* __restrict__ x1buf, const float* __restrict__ w2buf,
                        const float* __restrict__ a2c,
                        const int* __restrict__ off, const int* __restrict__ deg,
                        const int* __restrict__ col,
                        const float* __restrict__ lw, int hop,
                        bf16* __restrict__ hPn, bf16* __restrict__ hAn, bf16* __restrict__ hSn)
{
    int wid = (blockIdx.x * blockDim.x + threadIdx.x) >> 6;   // one wave per source node
    int lane = threadIdx.x & 63;
    int eo = lane >> 3, fl = lane & 7;
    if (wid >= NSRC) return;
    floatx8 r;
    bf16* dst;
    int n;
    if (wid < NP) {
        n = wid;
        bf16x8 xu = *(const bf16x8*)(xP + (size_t)n * 64 + fl * 8);
        floatx8 xv;
#pragma unroll
        for (int j = 0; j < 8; ++j) xv[j] = us2f((unsigned short)xu[j]);
        floatx8 r0 = agg_et8(n,           hop, 0, eo, fl, xv, x1buf, w2buf, a2c, hAo, off, deg, col);
        floatx8 r2 = agg_et8(NP + NA + n, hop, 2, eo, fl, xv, x1buf, w2buf, a2c, hSo, off, deg, col);
        float l0 = lw[hop * 4 + 0], l2 = lw[hop * 4 + 2];
        float mx = fmaxf(l0, l2);
        float e0 = __expf(l0 - mx), e2 = __expf(l2 - mx);
        float inv = 1.f / (e0 + e2);
#pragma unroll
        for (int j = 0; j < 8; ++j) r[j] = (e0 * r0[j] + e2 * r2[j]) * inv;
        dst = hPn;
    } else if (wid < NP + NA) {
        n = wid - NP;   // ap: softmax over single weight == 1
        bf16x8 xu = *(const bf16x8*)(xA + (size_t)n * 64 + fl * 8);
        floatx8 xv;
#pragma unroll
        for (int j = 0; j < 8; ++j) xv[j] = us2f((unsigned short)xu[j]);
        r = agg_et8(NP + n, hop, 1, eo, fl, xv, x1buf, w2buf, a2c, hPo, off, deg, col);
        dst = hAn;
    } else {
        n = wid - (NP + NA);  // sp
        bf16x8 xu = *(const bf16x8*)(xS + (size_t)n * 64 + fl * 8);
        floatx8 xv;
#pragma unroll
        for (int j = 0; j < 8; ++j) xv[j] = us2f((unsigned short)xu[j]);
        r = agg_et8(NP + NA + NP + n, hop, 3, eo, fl, xv, x1buf, w2buf, a2c, hPo, off, deg, col);
        dst = hSn;
    }
    if (eo == 0) {
        bf16x8 st;
#pragma unroll
        for (int j = 0; j < 8; ++j) st[j] = (short)f2bf_bits(eluf(r[j]));
        *(bf16x8*)(dst + (size_t)n * 64 + fl * 8) = st;
    }
}

// ---------------- fc2: out = hP @ W2^T + b2 (dual-dtype store) ----------------
__global__ void fc2_kernel(const bf16* __restrict__ hP, const float* __restrict__ W2,
                           const float* __restrict__ B2, void* __restrict__ out,
                           const int* __restrict__ flagp)
{
    int isb = *flagp;
    int idx = blockIdx.x * blockDim.x + threadIdx.x;
    if (idx >= NP * 16) return;
    int n = idx >> 4, o = idx & 15;
    float acc = B2[o];
    const bf16* hr = hP + (size_t)n * 64;
#pragma unroll
    for (int j = 0; j < 64; ++j) acc = fmaf(bf2f(hr[j]), W2[o * 64 + j], acc);
    if (isb) ((bf16*)out)[idx] = __float2bfloat16(acc);
    else     ((float*)out)[idx] = acc;
}

extern "C" void kernel_launch(void* const* d_in, const int* in_sizes, int n_in,
                              void* d_out, int out_size, void* d_ws, size_t ws_size,
                              hipStream_t stream)
{
    (void)in_sizes; (void)n_in; (void)out_size; (void)ws_size;
    const void* xPi  = d_in[0];
    const void* xAi  = d_in[1];
    const void* xSi  = d_in[2];
    const void* f1pw = d_in[3];
    const void* f1pb = d_in[4];
    const void* f1aw = d_in[5];
    const void* f1ab = d_in[6];
    const void* f1sw = d_in[7];
    const void* f1sb = d_in[8];
    const void* attn1 = d_in[9];
    const void* attn2 = d_in[10];
    const void* lwp  = d_in[11];
    const void* f2w  = d_in[12];
    const void* f2b  = d_in[13];
    const int* eipa = (const int*)d_in[14];
    const int* eiap = (const int*)d_in[15];
    const int* eips = (const int*)d_in[16];
    const int* eisp = (const int*)d_in[17];

    char* p = (char*)d_ws;
    auto alloc = [&](size_t bytes) { char* r = p; p += (bytes + 255) & ~(size_t)255; return r; };
    int*  flag = (int*)alloc(4);
    bf16* xP = (bf16*)alloc((size_t)NP * 64 * 2);
    bf16* xA = (bf16*)alloc((size_t)NA * 64 * 2);
    bf16* xS = (bf16*)alloc((size_t)NSJ * 64 * 2);
    bf16* hb[2][3];
    for (int qq = 0; qq < 2; ++qq) {
        hb[qq][0] = (bf16*)alloc((size_t)NP * 64 * 2);
        hb[qq][1] = (bf16*)alloc((size_t)NA * 64 * 2);
        hb[qq][2] = (bf16*)alloc((size_t)NSJ * 64 * 2);
    }
    float* x1buf = (float*)alloc((size_t)5 * NS_TOT * 4);
    float* w2buf = (float*)alloc((size_t)5 * NS_TOT * 4);
    int* cnt   = (int*)alloc((size_t)NS_TOT * 4);
    int* off   = (int*)alloc((size_t)NS_TOT * 4);
    int* rankv = (int*)alloc((size_t)ETOT * 4);
    int* posv  = (int*)alloc((size_t)ETOT * 4);
    int* colv  = (int*)alloc((size_t)ETOT * 4);
    int* partial  = (int*)alloc(512 * 4);
    int* chunkoff = (int*)alloc(512 * 4);
    float* a1c = (float*)alloc(1280 * 4);
    float* a2c = (float*)alloc(1280 * 4);
    float* lwc = (float*)alloc(20 * 4);
    float* w2c = (float*)alloc(1024 * 4);
    float* b2c = (float*)alloc(16 * 4);
    float* b1p = (float*)alloc(64 * 4);
    float* b1a = (float*)alloc(64 * 4);
    float* b1s = (float*)alloc(64 * 4);
    bf16* apack = (bf16*)alloc((size_t)4 * 2 * 1024 * 2);  // [k][hi|lo][16 rows][64] bf16

    // dtype flag + param normalization (single merged launch)
    detect_dtype<<<1, 64, 0, stream>>>((const unsigned int*)xPi, flag);
    conv_all<<<15, 256, 0, stream>>>(attn1, attn2, lwp, f2w, f2b, f1pb, f1ab, f1sb,
                                     a1c, a2c, lwc, w2c, b2c, b1p, b1a, b1s, flag);
    pack_attn<<<16, 256, 0, stream>>>(a1c, a2c, apack);

    // fc1 projections (x == h0, bf16), LDS-staged pipeline
    fc1_lds<512><<<(NP + 63) / 64, 256, 0, stream>>>(xPi, f1pw, b1p, NP, xP, flag);
    fc1_lds<256><<<(NA + 63) / 64, 256, 0, stream>>>(xAi, f1aw, b1a, NA, xA, flag);
    fc1_lds<128><<<(NSJ + 63) / 64, 256, 0, stream>>>(xSi, f1sw, b1s, NSJ, xS, flag);

    // per-source attention scalars for all hops (MFMA form)
    precompute_xw_mfma<<<(NSGRP + 3) / 4, 256, 0, stream>>>(xP, xA, xS, apack, x1buf, w2buf);

    // CSR build: rank -> scan -> pos -> bucketed scatter (atomic-free)
    hipMemsetAsync(cnt, 0, (size_t)NS_TOT * 4, stream);
    csr_rank<<<(ETOT + 255) / 256, 256, 0, stream>>>(eipa, eiap, eips, eisp, cnt, rankv);
    scan_reduce<<<NCHUNK, 256, 0, stream>>>(cnt, partial);
    scan_partials<<<1, 512, 0, stream>>>(partial, chunkoff);
    scan_write<<<NCHUNK, 256, 0, stream>>>(cnt, chunkoff, off);
    csr_pos<<<(ETOT + 255) / 256, 256, 0, stream>>>(eipa, eiap, eips, eisp, rankv, off, posv);
    csr_scatter<<<NSLICE * 8, 256, 0, stream>>>(eipa, eiap, eips, eisp, posv, colv);

    // hops: h(0) = x buffers; then alternate hb[0]/hb[1]; h1 fused into agg
    const bf16* cP = xP; const bf16* cA = xA; const bf16* cS = xS;
    for (int i = 0; i < 5; ++i) {
        bf16* nPb = hb[i & 1][0]; bf16* nAb = hb[i & 1][1]; bf16* nSb = hb[i & 1][2];
        hop_agg<<<(NSRC + 3) / 4, 256, 0, stream>>>(cP, cA, cS, xP, xA, xS,
                                                    x1buf, w2buf, a2c, off, cnt, colv,
                                                    lwc, i, nPb, nAb, nSb);
        cP = nPb; cA = nAb; cS = nSb;
    }

    fc2_kernel<<<(NP * 16 + 255) / 256, 256, 0, stream>>>(cP, w2c, b2c, d_out, flag);
}

// Round 6
// 1382.156 us; speedup vs baseline: 1.1986x; 1.1986x over previous
//
#include <hip/hip_runtime.h>
#include <hip/hip_bf16.h>

// HetGTAN 5-hop hetero graph attention, MI355X.
// Round 9: hop path restructured for wave efficiency. h1 un-fused (the per-
// edge recompute added 8 FMA + 3 dependent shuffles per edge; separate lean
// kernel is 4.5x less work). hop_agg: 4 nodes/wave x 16 lanes (2 edge-slots
// x 8 feats) - 4x fewer waves, combine tree 27->9 shuffles, deg-4 authors no
// longer idle half their edge slots.

#define NP 100000
#define NA 200000
#define NSJ 1000
#define EPA 800000
#define EAP 800000
#define EPS 100000
#define ESP 100000
#define ETOT 1800000
// source-slot concat: [paper(pa) | author(ap) | paper(ps) | subject(sp)]
#define NS_TOT 401000
// target-slot concat: [author(pa) | paper(ap) | subject(ps) | paper(sp)]
#define NT_TOT 401000
#define NSRC 301000
#define NCHUNK 392  // ceil(401000/1024)
#define NSGRP 25063 // ceil(401000/16)
#define SCAT_SLICE 4096
#define NSLICE ((ETOT + SCAT_SLICE - 1) / SCAT_SLICE)   // 440
#define BKT ((ETOT + 7) / 8)                            // 225000

typedef __attribute__((ext_vector_type(8))) short bf16x8;
typedef __attribute__((ext_vector_type(4))) float floatx4;
typedef __attribute__((ext_vector_type(8))) float floatx8;
typedef __hip_bfloat16 bf16;

__device__ __forceinline__ float bf2f(bf16 v) { return __bfloat162float(v); }
__device__ __forceinline__ float us2f(unsigned short u) { return __uint_as_float((unsigned)u << 16); }
__device__ __forceinline__ float eluf(float x) { return x > 0.f ? x : __expf(x) - 1.f; }
__device__ __forceinline__ unsigned short f2bf_bits(float f) {
    unsigned int u = __float_as_uint(f);
    return (unsigned short)((u + 0x7FFFu + ((u >> 16) & 1u)) >> 16);  // RNE
}

// async global->LDS, 16 B per lane, linear LDS dest (base + lane*16)
__device__ __forceinline__ void gload_lds16(const void* g, void* l) {
    __builtin_amdgcn_global_load_lds(
        (const __attribute__((address_space(1))) unsigned int*)g,
        (__attribute__((address_space(3))) unsigned int*)l, 16, 0, 0);
}

// fp32->bf16 MFMA fragment conversion load (fallback path)
__device__ __forceinline__ bf16x8 load_frag_f32(const void* base, size_t off) {
    const float4* f = (const float4*)((const float*)base + off);  // off%8==0 -> 16B aligned
    float4 a = f[0], b = f[1];
    bf16x8 r;
    r[0] = (short)f2bf_bits(a.x); r[1] = (short)f2bf_bits(a.y);
    r[2] = (short)f2bf_bits(a.z); r[3] = (short)f2bf_bits(a.w);
    r[4] = (short)f2bf_bits(b.x); r[5] = (short)f2bf_bits(b.y);
    r[6] = (short)f2bf_bits(b.z); r[7] = (short)f2bf_bits(b.w);
    return r;
}

// edge -> global source slot / target id from the 4 input edge arrays
__device__ __forceinline__ int edge_src(int e, const int* pa, const int* ap,
                                        const int* ps, const int* sp) {
    if (e < EPA)                  return pa[e];
    if (e < EPA + EAP)            return NP + ap[e - EPA];
    if (e < EPA + EAP + EPS)      return NP + NA + ps[e - (EPA + EAP)];
    return NP + NA + NP + sp[e - (EPA + EAP + EPS)];
}
__device__ __forceinline__ int edge_tgt(int e, const int* pa, const int* ap,
                                        const int* ps, const int* sp) {
    if (e < EPA)                  return pa[EPA + e];
    if (e < EPA + EAP)            return ap[EAP + (e - EPA)];
    if (e < EPA + EAP + EPS)      return ps[EPS + (e - (EPA + EAP))];
    return sp[ESP + (e - (EPA + EAP + EPS))];
}

// ---------------- dtype detection ----------------
__global__ void detect_dtype(const unsigned int* __restrict__ xraw, int* __restrict__ flag) {
    int t = threadIdx.x;   // 64 threads
    int hits = 0;
#pragma unroll
    for (int i = 0; i < 16; ++i) {
        unsigned int w = xraw[t * 16 + i];
        unsigned int lo = w & 0xFFFFu;
        unsigned int e = (lo >> 7) & 0xFFu;   // bf16 exponent field of low half
        if (lo == 0u || (e >= 110u && e <= 140u)) hits++;
    }
#pragma unroll
    for (int o = 32; o; o >>= 1) hits += __shfl_xor(hits, o);
    if (t == 0) *flag = (hits > 512) ? 1 : 0;   // bf16 ~99% hit, fp32 ~12%
}

// ---------------- merged param normalization to fp32 ----------------
__global__ void conv_all(const void* a1, const void* a2, const void* lw, const void* w2,
                         const void* b2, const void* bp, const void* ba, const void* bs,
                         float* a1c, float* a2c, float* lwc, float* w2c, float* b2c,
                         float* b1p, float* b1a, float* b1s, const int* __restrict__ flagp)
{
    int i = blockIdx.x * blockDim.x + threadIdx.x;
    int isb = *flagp;
    auto cv = [&](const void* s, int j) -> float {
        return isb ? bf2f(((const bf16*)s)[j]) : ((const float*)s)[j];
    };
    if (i < 1280)      a1c[i] = cv(a1, i);
    else if (i < 2560) a2c[i - 1280] = cv(a2, i - 1280);
    else if (i < 2580) lwc[i - 2560] = cv(lw, i - 2560);
    else if (i < 3604) w2c[i - 2580] = cv(w2, i - 2580);
    else if (i < 3620) b2c[i - 3604] = cv(b2, i - 3604);
    else if (i < 3684) b1p[i - 3620] = cv(bp, i - 3620);
    else if (i < 3748) b1a[i - 3684] = cv(ba, i - 3684);
    else if (i < 3812) b1s[i - 3748] = cv(bs, i - 3748);
}

// -------- pack attn vectors as B matrices for MFMA: per k, [16 rows][64] ------
__global__ void pack_attn(const float* __restrict__ a1c, const float* __restrict__ a2c,
                          bf16* __restrict__ apack)
{
    int i = blockIdx.x * blockDim.x + threadIdx.x;   // 4 k-slots * 1024
    if (i >= 4096) return;
    int k = i >> 10, rf = i & 1023;
    int row = rf >> 6;
    int f = rf & 63;
    float v = 0.f;
    if (row < 5)       v = a1c[(row * 4 + k) * 64 + f];
    else if (row < 10) v = a2c[((row - 5) * 4 + k) * 64 + f];
    unsigned short hi = f2bf_bits(v);
    float lo = v - us2f(hi);
    unsigned short* up = (unsigned short*)apack;
    up[(size_t)(k * 2) * 1024 + rf]     = hi;
    up[(size_t)(k * 2 + 1) * 1024 + rf] = f2bf_bits(lo);
}

// ---------------- fc1: x = relu(X @ W^T + b), W is [64,K]; writes bf16 -------
template<int K>
__global__ void fc1_lds(const void* __restrict__ X, const void* __restrict__ W,
                        const float* __restrict__ Bb, int N,
                        bf16* __restrict__ xo, const int* __restrict__ flagp)
{
    constexpr int NSTEP = K / 128;
    __shared__ __align__(16) unsigned char lds[2][64 * 256];   // [buf][row][chunk*16B]
    int isb = *flagp;
    int lane = threadIdx.x & 63;
    int wv = threadIdx.x >> 6;
    int row0 = blockIdx.x * 64;
    int m = lane & 15, kq = lane >> 4;
    floatx4 acc[4] = {};

    if (isb) {
        const bf16* Xb = (const bf16*)X;
        const bf16* Wb = (const bf16*)W;
        auto stage = [&](int s, int b) {
#pragma unroll
            for (int it = 0; it < 4; ++it) {
                int slotbase = (it * 4 + wv) * 64;    // wave-uniform
                int slot = slotbase + lane;
                int r = slot >> 4;
                int c = slot & 15;
                int rc = row0 + r; if (rc >= N) rc = N - 1;   // tail clamp
                int cs = c ^ (r & 15);                 // pre-swizzled source chunk
                const bf16* src = Xb + (size_t)rc * K + s * 128 + cs * 8;
                gload_lds16(src, &lds[b][slotbase * 16]);
            }
        };
        stage(0, 0);
        asm volatile("s_waitcnt vmcnt(0)" ::: "memory");
        __syncthreads();
        int R = wv * 16 + m;
#pragma unroll
        for (int s = 0; s < NSTEP; ++s) {
            if (s + 1 < NSTEP) stage(s + 1, (s + 1) & 1);   // async prefetch
            const unsigned char* bufp = lds[s & 1];
#pragma unroll
            for (int i = 0; i < 4; ++i) {
                int cs = (i * 4 + kq) ^ (R & 15);
                bf16x8 av = *(const bf16x8*)(bufp + R * 256 + cs * 16);
                int kg = s * 128 + i * 32 + kq * 8;
#pragma unroll
                for (int nb = 0; nb < 4; ++nb) {
                    bf16x8 bv = *(const bf16x8*)(Wb + (size_t)(nb * 16 + m) * K + kg);
                    acc[nb] = __builtin_amdgcn_mfma_f32_16x16x32_bf16(av, bv, acc[nb], 0, 0, 0);
                }
            }
            asm volatile("s_waitcnt vmcnt(0)" ::: "memory");   // prefetch landed
            __syncthreads();                                   // tile consumed by all waves
        }
    } else {
        // fp32 fallback: direct converting loads (rare path)
        int arow = row0 + wv * 16 + m;
        if (arow >= N) arow = N - 1;
#pragma unroll 4
        for (int i = 0; i < K / 32; ++i) {
            int k0 = i * 32 + kq * 8;
            bf16x8 av = load_frag_f32(X, (size_t)arow * K + k0);
#pragma unroll
            for (int nb = 0; nb < 4; ++nb) {
                bf16x8 bv = load_frag_f32(W, (size_t)(nb * 16 + m) * K + k0);
                acc[nb] = __builtin_amdgcn_mfma_f32_16x16x32_bf16(av, bv, acc[nb], 0, 0, 0);
            }
        }
    }
#pragma unroll
    for (int nb = 0; nb < 4; ++nb) {
#pragma unroll
        for (int r = 0; r < 4; ++r) {
            int row = row0 + wv * 16 + kq * 4 + r;   // C/D: row=(lane>>4)*4+reg, col=lane&15
            if (row < N) {
                int f = nb * 16 + m;
                float v = acc[nb][r] + Bb[f];
                xo[(size_t)row * 64 + f] = __float2bfloat16(fmaxf(v, 0.f));
            }
        }
    }
}

// ------- precompute x1 = x.a1, w2 = exp(lrelu(x1 + x.a2)) for all 5 hops -------
__global__ void precompute_xw_mfma(const bf16* __restrict__ xP, const bf16* __restrict__ xA,
                                   const bf16* __restrict__ xS,
                                   const bf16* __restrict__ apack,
                                   float* __restrict__ x1buf, float* __restrict__ w2buf)
{
    int wv = threadIdx.x >> 6;
    int lane = threadIdx.x & 63;
    int grp = blockIdx.x * 4 + wv;
    if (grp >= NSGRP) return;
    int base = grp * 16;
    int k, n0, nmax; const bf16* x;
    if (base < NP)                { k = 0; n0 = base;                  nmax = NP;  x = xP; }
    else if (base < NP + NA)      { k = 1; n0 = base - NP;             nmax = NA;  x = xA; }
    else if (base < NP + NA + NP) { k = 2; n0 = base - (NP + NA);      nmax = NP;  x = xP; }
    else                          { k = 3; n0 = base - (NP + NA + NP); nmax = NSJ; x = xS; }
    int m = lane & 15, kq = lane >> 4;
    int arow = n0 + m;
    if (arow >= nmax) arow = nmax - 1;      // clamp (subject tail)
    const bf16* bh = apack + (size_t)(k * 2) * 1024;
    const bf16* bl = bh + 1024;
    floatx4 acc = {};
#pragma unroll
    for (int ks = 0; ks < 64; ks += 32) {
        int k0 = ks + kq * 8;
        bf16x8 av  = *(const bf16x8*)(x  + (size_t)arow * 64 + k0);
        bf16x8 bvh = *(const bf16x8*)(bh + m * 64 + k0);
        bf16x8 bvl = *(const bf16x8*)(bl + m * 64 + k0);
        acc = __builtin_amdgcn_mfma_f32_16x16x32_bf16(av, bvh, acc, 0, 0, 0);
        acc = __builtin_amdgcn_mfma_f32_16x16x32_bf16(av, bvl, acc, 0, 0, 0);
    }
#pragma unroll
    for (int r = 0; r < 4; ++r) {
        float v = acc[r];
        float d2 = __shfl(v, lane + 5);     // same kq for m<11; only m<5 consumed
        int node = base + kq * 4 + r;
        if (m < 5 && node < NS_TOT) {
            x1buf[m * NS_TOT + node] = v;
            float z = v + d2;
            w2buf[m * NS_TOT + node] = __expf(z > 0.f ? z : 0.2f * z);
        }
    }
}

// ---------------- CSR build: rank -> scan -> pos -> bucketed scatter ----------------
__global__ void csr_rank(const int* __restrict__ pa, const int* __restrict__ ap,
                         const int* __restrict__ ps, const int* __restrict__ sp,
                         int* __restrict__ cnt, int* __restrict__ rank)
{
    int e = blockIdx.x * blockDim.x + threadIdx.x;
    if (e >= ETOT) return;
    int g = edge_src(e, pa, ap, ps, sp);
    rank[e] = atomicAdd(&cnt[g], 1);
}

__global__ void scan_reduce(const int* __restrict__ cnt, int* __restrict__ partial)
{
    __shared__ int s[256];
    int base = blockIdx.x * 1024 + threadIdx.x * 4;
    int sum = 0;
#pragma unroll
    for (int r = 0; r < 4; ++r) { int i = base + r; if (i < NS_TOT) sum += cnt[i]; }
    s[threadIdx.x] = sum; __syncthreads();
    for (int o = 128; o; o >>= 1) {
        if (threadIdx.x < o) s[threadIdx.x] += s[threadIdx.x + o];
        __syncthreads();
    }
    if (!threadIdx.x) partial[blockIdx.x] = s[0];
}

__global__ void scan_partials(const int* __restrict__ partial, int* __restrict__ chunkoff)
{
    __shared__ int s[512];
    int t = threadIdx.x;
    int v = (t < NCHUNK) ? partial[t] : 0;
    s[t] = v; __syncthreads();
    for (int o = 1; o < 512; o <<= 1) {
        int add = (t >= o) ? s[t - o] : 0;
        __syncthreads();
        s[t] += add; __syncthreads();
    }
    if (t < NCHUNK) chunkoff[t] = s[t] - v;   // exclusive
}

__global__ void scan_write(const int* __restrict__ cnt, const int* __restrict__ chunkoff,
                           int* __restrict__ off)
{
    __shared__ int s[256];
    int t = threadIdx.x;
    int base = blockIdx.x * 1024 + t * 4;
    int v[4]; int tsum = 0;
#pragma unroll
    for (int r = 0; r < 4; ++r) { int i = base + r; v[r] = (i < NS_TOT) ? cnt[i] : 0; tsum += v[r]; }
    s[t] = tsum; __syncthreads();
    for (int o = 1; o < 256; o <<= 1) {
        int add = (t >= o) ? s[t - o] : 0;
        __syncthreads();
        s[t] += add; __syncthreads();
    }
    int excl = s[t] - tsum + chunkoff[blockIdx.x];
#pragma unroll
    for (int r = 0; r < 4; ++r) {
        int i = base + r;
        if (i < NS_TOT) { off[i] = excl; excl += v[r]; }
    }
}

__global__ void csr_pos(const int* __restrict__ pa, const int* __restrict__ ap,
                        const int* __restrict__ ps, const int* __restrict__ sp,
                        const int* __restrict__ rank, const int* __restrict__ off,
                        int* __restrict__ pos)
{
    int e = blockIdx.x * blockDim.x + threadIdx.x;
    if (e >= ETOT) return;
    int g = edge_src(e, pa, ap, ps, sp);
    pos[e] = off[g] + rank[e];
}

__global__ void csr_scatter(const int* __restrict__ pa, const int* __restrict__ ap,
                            const int* __restrict__ ps, const int* __restrict__ sp,
                            const int* __restrict__ pos, int* __restrict__ col)
{
    int b = blockIdx.x & 7;
    int slice = blockIdx.x >> 3;
    int lo = b * BKT;
    int hi = lo + BKT; if (hi > ETOT) hi = ETOT;
    int ebase = slice * SCAT_SLICE;
    int eend = ebase + SCAT_SLICE; if (eend > ETOT) eend = ETOT;
    for (int e = ebase + threadIdx.x; e < eend; e += 256) {
        int p = pos[e];
        if (p < lo || p >= hi) continue;
        col[p] = edge_tgt(e, pa, ap, ps, sp);
    }
}

// ------- per hop: h1[t] = h_old[t] . a2[hop,k]; 8 targets/wave x 8 feats -------
__global__ void hop_h1(const bf16* __restrict__ hP, const bf16* __restrict__ hA,
                       const bf16* __restrict__ hS,
                       const float* __restrict__ a2c, int hop, float* __restrict__ h1)
{
    int wave = (blockIdx.x * blockDim.x + threadIdx.x) >> 6;
    int lane = threadIdx.x & 63;
    int eo = lane >> 3, fl = lane & 7;
    int wid = wave * 8 + eo;
    if (wid >= NT_TOT) return;
    int k, n; const bf16* h;
    if (wid < NA)                 { k = 0; n = wid;               h = hA; }
    else if (wid < NA + NP)       { k = 1; n = wid - NA;          h = hP; }
    else if (wid < NA + NP + NSJ) { k = 2; n = wid - (NA + NP);   h = hS; }
    else                          { k = 3; n = wid - (NA+NP+NSJ); h = hP; }
    bf16x8 hv = *(const bf16x8*)(h + (size_t)n * 64 + fl * 8);
    const float4* a2p = (const float4*)(a2c + (hop * 4 + k) * 64 + fl * 8);
    float4 aa = a2p[0], ab = a2p[1];
    float v = us2f((unsigned short)hv[0]) * aa.x;
    v = fmaf(us2f((unsigned short)hv[1]), aa.y, v);
    v = fmaf(us2f((unsigned short)hv[2]), aa.z, v);
    v = fmaf(us2f((unsigned short)hv[3]), aa.w, v);
    v = fmaf(us2f((unsigned short)hv[4]), ab.x, v);
    v = fmaf(us2f((unsigned short)hv[5]), ab.y, v);
    v = fmaf(us2f((unsigned short)hv[6]), ab.z, v);
    v = fmaf(us2f((unsigned short)hv[7]), ab.w, v);
    v += __shfl_xor(v, 1);
    v += __shfl_xor(v, 2);
    v += __shfl_xor(v, 4);
    if (fl == 0) h1[wid] = v;
}

// ------- per hop: 4 nodes/wave, 16 lanes/node (2 edge-slots x 8 feats) -------
__device__ __forceinline__ floatx8 agg_et16(int g, int hop, int eo2, int fl, floatx8 xv,
    const float* __restrict__ x1buf, const float* __restrict__ w2buf,
    const float* __restrict__ h1, int h1base, const bf16* __restrict__ ht,
    const int* __restrict__ off, const int* __restrict__ deg, const int* __restrict__ col)
{
    float x1v = x1buf[hop * NS_TOT + g];
    const float* h1p = h1 + h1base;
    floatx8 acc = {};
    float dv = 0.f;
    int e0 = off[g];
    int e1 = e0 + deg[g];
    for (int e = e0 + eo2; e < e1; e += 2) {
        int t = col[e];
        float z = x1v + h1p[t];
        float w1 = __expf(z > 0.f ? z : 0.2f * z);
        bf16x8 hv = *(const bf16x8*)(ht + (size_t)t * 64 + fl * 8);
#pragma unroll
        for (int j = 0; j < 8; ++j)
            acc[j] = fmaf(w1, us2f((unsigned short)hv[j]), acc[j]);
        dv += w1;
    }
    // combine the 2 edge-slots (within the 16-lane node segment)
#pragma unroll
    for (int j = 0; j < 8; ++j) acc[j] += __shfl_xor(acc[j], 8);
    dv += __shfl_xor(dv, 8);
    float w2v = w2buf[hop * NS_TOT + g];
    dv += w2v;
    float inv = 1.f / dv;
    floatx8 r;
#pragma unroll
    for (int j = 0; j < 8; ++j) r[j] = (acc[j] + w2v * xv[j]) * inv;
    return r;
}

__global__ void hop_agg(const bf16* __restrict__ hPo, const bf16* __restrict__ hAo,
                        const bf16* __restrict__ hSo,
                        const bf16* __restrict__ xP, const bf16* __restrict__ xA,
                        const bf16* __restrict__ xS,
                        const float* __restrict__ x1buf, const float* __restrict__ w2buf,
                        const float* __restrict__ h1,
                        const int* __restrict__ off, const int* __restrict__ deg,
                        const int* __restrict__ col,
                        const float* __restrict__ lw, int hop,
                        bf16* __restrict__ hPn, bf16* __restrict__ hAn, bf16* __restrict__ hSn)
{
    int wave = (blockIdx.x * blockDim.x + threadIdx.x) >> 6;
    int lane = threadIdx.x & 63;
    int seg = lane >> 4;                    // node slot 0..3 within wave
    int l16 = lane & 15;
    int eo2 = l16 >> 3, fl = l16 & 7;       // edge-slot, feature-octet
    int wid = wave * 4 + seg;
    if (wid >= NSRC) return;
    floatx8 r;
    bf16* dst;
    int n;
    if (wid < NP) {
        n = wid;
        bf16x8 xu = *(const bf16x8*)(xP + (size_t)n * 64 + fl * 8);
        floatx8 xv;
#pragma unroll
        for (int j = 0; j < 8; ++j) xv[j] = us2f((unsigned short)xu[j]);
        floatx8 r0 = agg_et16(n,           hop, eo2, fl, xv, x1buf, w2buf, h1, 0,       hAo, off, deg, col);
        floatx8 r2 = agg_et16(NP + NA + n, hop, eo2, fl, xv, x1buf, w2buf, h1, NA + NP, hSo, off, deg, col);
        float l0 = lw[hop * 4 + 0], l2 = lw[hop * 4 + 2];
        float mx = fmaxf(l0, l2);
        float e0 = __expf(l0 - mx), e2 = __expf(l2 - mx);
        float inv = 1.f / (e0 + e2);
#pragma unroll
        for (int j = 0; j < 8; ++j) r[j] = (e0 * r0[j] + e2 * r2[j]) * inv;
        dst = hPn;
    } else if (wid < NP + NA) {
        n = wid - NP;   // ap: softmax over single weight == 1
        bf16x8 xu = *(const bf16x8*)(xA + (size_t)n * 64 + fl * 8);
        floatx8 xv;
#pragma unroll
        for (int j = 0; j < 8; ++j) xv[j] = us2f((unsigned short)xu[j]);
        r = agg_et16(NP + n, hop, eo2, fl, xv, x1buf, w2buf, h1, NA, hPo, off, deg, col);
        dst = hAn;
    } else {
        n = wid - (NP + NA);  // sp
        bf16x8 xu = *(const bf16x8*)(xS + (size_t)n * 64 + fl * 8);
        floatx8 xv;
#pragma unroll
        for (int j = 0; j < 8; ++j) xv[j] = us2f((unsigned short)xu[j]);
        r = agg_et16(NP + NA + NP + n, hop, eo2, fl, xv, x1buf, w2buf, h1, NA + NP + NSJ, hPo, off, deg, col);
        dst = hSn;
    }
    if (eo2 == 0) {
        bf16x8 st;
#pragma unroll
        for (int j = 0; j < 8; ++j) st[j] = (short)f2bf_bits(eluf(r[j]));
        *(bf16x8*)(dst + (size_t)n * 64 + fl * 8) = st;
    }
}

// ---------------- fc2: out = hP @ W2^T + b2 (dual-dtype store) ----------------
__global__ void fc2_kernel(const bf16* __restrict__ hP, const float* __restrict__ W2,
                           const float* __restrict__ B2, void* __restrict__ out,
                           const int* __restrict__ flagp)
{
    int isb = *flagp;
    int idx = blockIdx.x * blockDim.x + threadIdx.x;
    if (idx >= NP * 16) return;
    int n = idx >> 4, o = idx & 15;
    float acc = B2[o];
    const bf16* hr = hP + (size_t)n * 64;
#pragma unroll
    for (int j = 0; j < 64; ++j) acc = fmaf(bf2f(hr[j]), W2[o * 64 + j], acc);
    if (isb) ((bf16*)out)[idx] = __float2bfloat16(acc);
    else     ((float*)out)[idx] = acc;
}

extern "C" void kernel_launch(void* const* d_in, const int* in_sizes, int n_in,
                              void* d_out, int out_size, void* d_ws, size_t ws_size,
                              hipStream_t stream)
{
    (void)in_sizes; (void)n_in; (void)out_size; (void)ws_size;
    const void* xPi  = d_in[0];
    const void* xAi  = d_in[1];
    const void* xSi  = d_in[2];
    const void* f1pw = d_in[3];
    const void* f1pb = d_in[4];
    const void* f1aw = d_in[5];
    const void* f1ab = d_in[6];
    const void* f1sw = d_in[7];
    const void* f1sb = d_in[8];
    const void* attn1 = d_in[9];
    const void* attn2 = d_in[10];
    const void* lwp  = d_in[11];
    const void* f2w  = d_in[12];
    const void* f2b  = d_in[13];
    const int* eipa = (const int*)d_in[14];
    const int* eiap = (const int*)d_in[15];
    const int* eips = (const int*)d_in[16];
    const int* eisp = (const int*)d_in[17];

    char* p = (char*)d_ws;
    auto alloc = [&](size_t bytes) { char* r = p; p += (bytes + 255) & ~(size_t)255; return r; };
    int*  flag = (int*)alloc(4);
    bf16* xP = (bf16*)alloc((size_t)NP * 64 * 2);
    bf16* xA = (bf16*)alloc((size_t)NA * 64 * 2);
    bf16* xS = (bf16*)alloc((size_t)NSJ * 64 * 2);
    bf16* hb[2][3];
    for (int qq = 0; qq < 2; ++qq) {
        hb[qq][0] = (bf16*)alloc((size_t)NP * 64 * 2);
        hb[qq][1] = (bf16*)alloc((size_t)NA * 64 * 2);
        hb[qq][2] = (bf16*)alloc((size_t)NSJ * 64 * 2);
    }
    float* x1buf = (float*)alloc((size_t)5 * NS_TOT * 4);
    float* w2buf = (float*)alloc((size_t)5 * NS_TOT * 4);
    float* h1v  = (float*)alloc((size_t)NT_TOT * 4);
    int* cnt   = (int*)alloc((size_t)NS_TOT * 4);
    int* off   = (int*)alloc((size_t)NS_TOT * 4);
    int* rankv = (int*)alloc((size_t)ETOT * 4);
    int* posv  = (int*)alloc((size_t)ETOT * 4);
    int* colv  = (int*)alloc((size_t)ETOT * 4);
    int* partial  = (int*)alloc(512 * 4);
    int* chunkoff = (int*)alloc(512 * 4);
    float* a1c = (float*)alloc(1280 * 4);
    float* a2c = (float*)alloc(1280 * 4);
    float* lwc = (float*)alloc(20 * 4);
    float* w2c = (float*)alloc(1024 * 4);
    float* b2c = (float*)alloc(16 * 4);
    float* b1p = (float*)alloc(64 * 4);
    float* b1a = (float*)alloc(64 * 4);
    float* b1s = (float*)alloc(64 * 4);
    bf16* apack = (bf16*)alloc((size_t)4 * 2 * 1024 * 2);  // [k][hi|lo][16 rows][64] bf16

    // dtype flag + param normalization (single merged launch)
    detect_dtype<<<1, 64, 0, stream>>>((const unsigned int*)xPi, flag);
    conv_all<<<15, 256, 0, stream>>>(attn1, attn2, lwp, f2w, f2b, f1pb, f1ab, f1sb,
                                     a1c, a2c, lwc, w2c, b2c, b1p, b1a, b1s, flag);
    pack_attn<<<16, 256, 0, stream>>>(a1c, a2c, apack);

    // fc1 projections (x == h0, bf16), LDS-staged pipeline
    fc1_lds<512><<<(NP + 63) / 64, 256, 0, stream>>>(xPi, f1pw, b1p, NP, xP, flag);
    fc1_lds<256><<<(NA + 63) / 64, 256, 0, stream>>>(xAi, f1aw, b1a, NA, xA, flag);
    fc1_lds<128><<<(NSJ + 63) / 64, 256, 0, stream>>>(xSi, f1sw, b1s, NSJ, xS, flag);

    // per-source attention scalars for all hops (MFMA form)
    precompute_xw_mfma<<<(NSGRP + 3) / 4, 256, 0, stream>>>(xP, xA, xS, apack, x1buf, w2buf);

    // CSR build: rank -> scan -> pos -> bucketed scatter (atomic-free)
    hipMemsetAsync(cnt, 0, (size_t)NS_TOT * 4, stream);
    csr_rank<<<(ETOT + 255) / 256, 256, 0, stream>>>(eipa, eiap, eips, eisp, cnt, rankv);
    scan_reduce<<<NCHUNK, 256, 0, stream>>>(cnt, partial);
    scan_partials<<<1, 512, 0, stream>>>(partial, chunkoff);
    scan_write<<<NCHUNK, 256, 0, stream>>>(cnt, chunkoff, off);
    csr_pos<<<(ETOT + 255) / 256, 256, 0, stream>>>(eipa, eiap, eips, eisp, rankv, off, posv);
    csr_scatter<<<NSLICE * 8, 256, 0, stream>>>(eipa, eiap, eips, eisp, posv, colv);

    // hops: h(0) = x buffers; then alternate hb[0]/hb[1]
    const bf16* cP = xP; const bf16* cA = xA; const bf16* cS = xS;
    for (int i = 0; i < 5; ++i) {
        bf16* nPb = hb[i & 1][0]; bf16* nAb = hb[i & 1][1]; bf16* nSb = hb[i & 1][2];
        hop_h1<<<(NT_TOT / 8 + 4) / 4, 256, 0, stream>>>(cP, cA, cS, a2c, i, h1v);
        hop_agg<<<((NSRC + 3) / 4 + 3) / 4, 256, 0, stream>>>(cP, cA, cS, xP, xA, xS,
                                                    x1buf, w2buf, h1v, off, cnt, colv,
                                                    lwc, i, nPb, nAb, nSb);
        cP = nPb; cA = nAb; cS = nSb;
    }

    fc2_kernel<<<(NP * 16 + 255) / 256, 256, 0, stream>>>(cP, w2c, b2c, d_out, flag);
}